// Round 19
// baseline (53.302 us; speedup 1.0000x reference)
//
#include <hip/hip_runtime.h>
#include <math.h>
#include <limits.h>

#define EPSF 1e-6f
#define THR 0.5f
#define PUSH_W 1.0f
#define PULL_W 1.0f

constexpr int BN = 2048;    // proposals per batch
constexpr int BG = 64;      // gt boxes per batch

__device__ __forceinline__ float iou_box(float4 a, float4 b) {
  float aa = (a.z - a.x) * (a.w - a.y);
  float ab = (b.z - b.x) * (b.w - b.y);
  float w = fmaxf(fminf(a.z, b.z) - fmaxf(a.x, b.x), 0.f);
  float h = fmaxf(fminf(a.w, b.w) - fmaxf(a.y, b.y), 0.f);
  float inter = w * h;
  return inter / (aa + ab - inter + EPSF);
}

// 64x64 bit-matrix transpose: lane l holds row l as u64; returns column l.
__device__ __forceinline__ unsigned long long bittr64(unsigned long long row, int lane) {
  const unsigned long long M0 = 0x00000000FFFFFFFFull;
  const unsigned long long M1 = 0x0000FFFF0000FFFFull;
  const unsigned long long M2 = 0x00FF00FF00FF00FFull;
  const unsigned long long M3 = 0x0F0F0F0F0F0F0F0Full;
  const unsigned long long M4 = 0x3333333333333333ull;
  const unsigned long long M5 = 0x5555555555555555ull;
#define TSTEP(m, j)                                                      \
  {                                                                      \
    unsigned long long t = __shfl_xor(row, j);                           \
    if ((lane & (j)) == 0) row = (row & (m)) | ((t & (m)) << (j));       \
    else                   row = (row & ~(m)) | ((t >> (j)) & (m));      \
  }
  TSTEP(M0, 32) TSTEP(M1, 16) TSTEP(M2, 8) TSTEP(M3, 4) TSTEP(M4, 2) TSTEP(M5, 1)
#undef TSTEP
  return row;
}

// ------------------------------- K1: rank-by-count sort (8 threads per row)
__global__ __launch_bounds__(512) void k1_sort(
    const int* __restrict__ gti_all, const float* __restrict__ gtb_all,
    const float* __restrict__ prop_all,
    float4* __restrict__ boxs, float* __restrict__ pers,
    short* __restrict__ gtss, float* __restrict__ scs,
    int* __restrict__ arrive)
{
  const int b = blockIdx.x & 7;        // batch
  const int sub = blockIdx.x >> 3;     // 0..31 (64 rows each)
  const int tid = threadIdx.x;
  __shared__ unsigned long long key[BN];   // 16 KB

  if (blockIdx.x == 0 && tid == 0) *arrive = 0;   // defensive reset (pre-k3)

  const float* P = prop_all + (size_t)b * BN * 5;
  const int* gti = gti_all + b * BN;
  const float* GB = gtb_all + b * BG * 4;

  for (int k = 0; k < 4; ++k) {
    int j = tid + k * 512;
    key[j] = ((unsigned long long)__float_as_uint(P[j * 5 + 4]) << 32) |
             (unsigned)(BN - 1 - j);
  }
  __syncthreads();

  const int r = sub * 64 + (tid >> 3);
  const int g8 = tid & 7;
  const unsigned long long myk = key[r];
  int cnt = 0;
  const ulonglong2* K2 = (const ulonglong2*)key;
#pragma unroll 8
  for (int i = 0; i < 128; ++i) {
    ulonglong2 kk = K2[g8 + 8 * i];    // 8-group, conflict-free
    cnt += (kk.x > myk) ? 1 : 0;
    cnt += (kk.y > myk) ? 1 : 0;
  }
  cnt += __shfl_down(cnt, 4, 8);
  cnt += __shfl_down(cnt, 2, 8);
  cnt += __shfl_down(cnt, 1, 8);
  if (g8 == 0) {
    const int rank = cnt;
    int idx = (BN - 1) - (int)(myk & 0xffffffffu);
    float x1 = P[idx * 5 + 0], y1 = P[idx * 5 + 1];
    float x2 = P[idx * 5 + 2], y2 = P[idx * 5 + 3];
    float s = __uint_as_float((unsigned)(myk >> 32));
    int g = gti[idx];
    float4 bx = make_float4(x1, y1, x2, y2);
    boxs[b * BN + rank] = bx;
    scs[b * BN + rank] = s;
    gtss[b * BN + rank] = (short)g;
    float pv = 0.f;
    if (g >= 0) {
      float4 gb = make_float4(GB[g * 4], GB[g * 4 + 1], GB[g * 4 + 2], GB[g * 4 + 3]);
      pv = -logf(EPSF + iou_box(gb, bx)) * s;
    }
    pers[b * BN + rank] = pv;
  }
}

// ---------------- K2: adjacency, triangular tiles + bit-transpose mirror
// grid = nb*36; tile (rg, ct) with ct >= rg covers rows rg*256..+256,
// cols ct*256..+256; mirror (if ct>rg) written via 64x64 bit transpose.
__global__ __launch_bounds__(512) void k2_adj(
    const float4* __restrict__ boxs, uint2* __restrict__ adjC)
{
  const int b = blockIdx.x & 7;
  const int t = blockIdx.x >> 3;         // 0..35
  int rg = 0, acc = 0;
  while (acc + (8 - rg) <= t) { acc += 8 - rg; rg++; }
  const int ct = rg + (t - acc);

  const int tid = threadIdx.x;           // 0..511
  const int lane = tid & 63;
  const int w = tid >> 6;                // wave 0..7
  const int rh = w >> 2;                 // row half 0/1
  const int cc = w & 3;                  // col chunk 0..3
  __shared__ float4 bs[256];             // 4 KB column tile

  const float4* B = boxs + b * BN;
  if (tid < 256) bs[tid] = B[ct * 256 + tid];

  const int row0 = rg * 256 + rh * 128 + lane;   // sub-block rb = rh*2
  const int row1 = row0 + 64;                    // sub-block rb = rh*2+1
  const float4 r0 = B[row0];
  const float4 r1 = B[row1];
  const float a0 = (r0.z - r0.x) * (r0.w - r0.y) + EPSF;
  const float a1 = (r1.z - r1.x) * (r1.w - r1.y) + EPSF;
  __syncthreads();

  const float4* C = &bs[cc * 64];
  unsigned lo0 = 0, hi0 = 0, lo1 = 0, hi1 = 0;

#define PRED(RR, AA, BJ, AB)                                              \
  (3.0f * (fmaxf(fminf(RR.z, BJ.z) - fmaxf(RR.x, BJ.x), 0.f) *            \
           fmaxf(fminf(RR.w, BJ.w) - fmaxf(RR.y, BJ.y), 0.f)) > AA + AB)

#pragma unroll 8
  for (int jj = 0; jj < 32; ++jj) {
    float4 bj = C[jj];                   // wave-uniform -> LDS broadcast
    float ab = (bj.z - bj.x) * (bj.w - bj.y);
    lo0 |= PRED(r0, a0, bj, ab) ? (1u << jj) : 0u;
    lo1 |= PRED(r1, a1, bj, ab) ? (1u << jj) : 0u;
  }
#pragma unroll 8
  for (int jj = 0; jj < 32; ++jj) {
    float4 bj = C[32 + jj];
    float ab = (bj.z - bj.x) * (bj.w - bj.y);
    hi0 |= PRED(r0, a0, bj, ab) ? (1u << jj) : 0u;
    hi1 |= PRED(r1, a1, bj, ab) ? (1u << jj) : 0u;
  }
#undef PRED

  // tile write: chunk ct*4+cc, rows row0/row1
  uint2* CO = adjC + ((size_t)b * 32 + ct * 4 + cc) * 2048;
  CO[row0] = make_uint2(lo0, hi0);
  CO[row1] = make_uint2(lo1, hi1);

  if (ct != rg) {
    // mirror via symmetry: transpose the two 64x64 bit sub-blocks
    unsigned long long t0 = ((unsigned long long)hi0 << 32) | (unsigned long long)lo0;
    unsigned long long t1 = ((unsigned long long)hi1 << 32) | (unsigned long long)lo1;
    t0 = bittr64(t0, lane);
    t1 = bittr64(t1, lane);
    const int mrow = ct * 256 + cc * 64 + lane;
    uint2* M0 = adjC + ((size_t)b * 32 + rg * 4 + rh * 2) * 2048;
    uint2* M1 = adjC + ((size_t)b * 32 + rg * 4 + rh * 2 + 1) * 2048;
    M0[mrow] = make_uint2((unsigned)t0, (unsigned)(t0 >> 32));
    M1[mrow] = make_uint2((unsigned)t1, (unsigned)(t1 >> 32));
  }
}

// ---------- K3 fused: triangular 8-round resolve + fsc events + loss
#define QR(B, K, Q) B##_##K##_##Q

#define DECL16(B) \
  uint2 QR(B,0,0), QR(B,0,1), QR(B,0,2), QR(B,0,3), \
        QR(B,1,0), QR(B,1,1), QR(B,1,2), QR(B,1,3), \
        QR(B,2,0), QR(B,2,1), QR(B,2,2), QR(B,2,3), \
        QR(B,3,0), QR(B,3,1), QR(B,3,2), QR(B,3,3);

#define LOADCH(B, K, C) \
  QR(B,K,0) = Cb[(size_t)(C) * 2048 + wbase]; \
  QR(B,K,1) = Cb[(size_t)(C) * 2048 + wbase + 64]; \
  QR(B,K,2) = Cb[(size_t)(C) * 2048 + wbase + 128]; \
  QR(B,K,3) = Cb[(size_t)(C) * 2048 + wbase + 192];

#define LOAD16(B, RR) \
  LOADCH(B, 0, (RR)*4+0) LOADCH(B, 1, (RR)*4+1) \
  LOADCH(B, 2, (RR)*4+2) LOADCH(B, 3, (RR)*4+3)

// scalar-domain greedy pick: one ballot, then s_ff1 + readlane per pick
#define PICK(B, K, C)                                                          \
  {                                                                            \
    unsigned mybit = ((act >> (K)) & ~(supG >> (K))) & 1u;                     \
    unsigned long long cand = __ballot(mybit != 0u);                           \
    unsigned long long pickw = 0ull;                                           \
    while (cand) {                                                             \
      int bpos = (int)__ffsll(cand) - 1;                                       \
      pickw |= 1ull << bpos;                                                   \
      unsigned rlo = __builtin_amdgcn_readlane(QR(B,K,K).x, bpos);             \
      unsigned rhi = __builtin_amdgcn_readlane(QR(B,K,K).y, bpos);             \
      cand &= ~((((unsigned long long)rhi) << 32) | (unsigned long long)rlo);  \
      cand &= ~(1ull << bpos);                                                 \
    }                                                                          \
    if (lane == 0) {                                                           \
      pm_lds[2 * (C)] = (unsigned)pickw;                                       \
      pm_lds[2 * (C) + 1] = (unsigned)(pickw >> 32);                           \
    }                                                                          \
    if (pickw != 0ull) {                                                       \
      unsigned pwlo = (unsigned)pickw, pwhi = (unsigned)(pickw >> 32);         \
      { unsigned hit = (QR(B,K,0).x & pwlo) | (QR(B,K,0).y & pwhi); supG |= (hit ? 1u : 0u); }      \
      { unsigned hit = (QR(B,K,1).x & pwlo) | (QR(B,K,1).y & pwhi); supG |= (hit ? 2u : 0u); }      \
      { unsigned hit = (QR(B,K,2).x & pwlo) | (QR(B,K,2).y & pwhi); supG |= (hit ? 4u : 0u); }      \
      { unsigned hit = (QR(B,K,3).x & pwlo) | (QR(B,K,3).y & pwhi); supG |= (hit ? 8u : 0u); }      \
    }                                                                          \
  }

#define APPLY(B, K, C)                                                         \
  {                                                                            \
    unsigned pwlo = pm_lds[2 * (C)], pwhi = pm_lds[2 * (C) + 1];               \
    if ((pwlo | pwhi) != 0u) {                                                 \
      unsigned nbits = 0;                                                      \
      { unsigned hit = (QR(B,K,0).x & pwlo) | (QR(B,K,0).y & pwhi); nbits |= hit ? 1u : 0u; }       \
      { unsigned hit = (QR(B,K,1).x & pwlo) | (QR(B,K,1).y & pwhi); nbits |= hit ? 2u : 0u; }       \
      { unsigned hit = (QR(B,K,2).x & pwlo) | (QR(B,K,2).y & pwhi); nbits |= hit ? 4u : 0u; }       \
      { unsigned hit = (QR(B,K,3).x & pwlo) | (QR(B,K,3).y & pwhi); nbits |= hit ? 8u : 0u; }       \
      unsigned flips = nbits & ~sup;                                           \
      sup |= nbits;                                                            \
      while (flips) {                                                          \
        int fq = __ffs(flips) - 1; flips &= flips - 1;                         \
        fsc_s[wbase + fq * 64] = (unsigned char)(C);                           \
      }                                                                        \
    }                                                                          \
  }

// triangular: wave o settled after round o -> loads gated wave>RR, APPLY wave>=RR
#define ROUND(RR, CUR, NXT)                                                    \
  {                                                                            \
    if (((RR) + 1 < 8) && (wave > (RR))) { LOAD16(NXT, (RR) + 1) }             \
    if (wave == (RR)) {                                                        \
      unsigned supG = sup;                                                     \
      PICK(CUR, 0, (RR)*4 + 0)                                                 \
      PICK(CUR, 1, (RR)*4 + 1)                                                 \
      PICK(CUR, 2, (RR)*4 + 2)                                                 \
      PICK(CUR, 3, (RR)*4 + 3)                                                 \
      asm volatile("s_waitcnt lgkmcnt(0)" ::: "memory");                       \
    }                                                                          \
    __builtin_amdgcn_s_barrier();                                              \
    asm volatile("" ::: "memory");                                             \
    if (wave >= (RR)) {                                                        \
      APPLY(CUR, 0, (RR)*4 + 0)                                                \
      APPLY(CUR, 1, (RR)*4 + 1)                                                \
      APPLY(CUR, 2, (RR)*4 + 2)                                                \
      APPLY(CUR, 3, (RR)*4 + 3)                                                \
    }                                                                          \
  }

__global__ __launch_bounds__(512, 1) void k3_fused(
    const float4* __restrict__ boxs, const float* __restrict__ pers,
    const short* __restrict__ gtss, const float* __restrict__ scs,
    const uint2* __restrict__ adjC, float* __restrict__ bp,
    int* __restrict__ arrive, float* __restrict__ out, int nb)
{
  const int b = blockIdx.x;
  const int tid = threadIdx.x;        // 0..511
  const int lane = tid & 63;
  const int wave = tid >> 6;          // 0..7

  __shared__ float qs_s[BN];          // 8 KB
  __shared__ int qc_s[BN];            // 8 KB
  __shared__ unsigned short ev_s[BN]; // 4 KB
  __shared__ short gts_s[BN];         // 4 KB
  __shared__ unsigned char fsc_s[BN]; // 2 KB
  __shared__ unsigned pm_lds[64];
  __shared__ unsigned pre_s[64];
  __shared__ int fpr_s[64];
  __shared__ unsigned hp_s[64];
  __shared__ int lastrem_s, npick_s, npos_s;
  __shared__ float redp[8][4];

  const uint2* Cb = adjC + (size_t)b * 32 * 2048;
  const int wbase = wave * 256 + lane;   // my q=0 rank

  // ---- prologue: issue round-0 loads + act from GLOBAL before LDS init ----
  DECL16(X)
  DECL16(Y)
  LOAD16(X, 0)
  unsigned act = 0;
  if (gtss[b * BN + wbase +   0] >= 0) act |= 1u;
  if (gtss[b * BN + wbase +  64] >= 0) act |= 2u;
  if (gtss[b * BN + wbase + 128] >= 0) act |= 4u;
  if (gtss[b * BN + wbase + 192] >= 0) act |= 8u;

  // ---- phase A: init + stage gts (overlaps in-flight loads) ----
  for (int k = tid; k < BN / 2; k += 512)
    ((int*)gts_s)[k] = ((const int*)(gtss + b * BN))[k];
  for (int k = tid; k < BN; k += 512) { qs_s[k] = 0.f; qc_s[k] = 0; }
  for (int k = tid; k < BN; k += 512) fsc_s[k] = 255;
  if (tid < 64) { fpr_s[tid] = INT_MAX; hp_s[tid] = 0u; }
  if (tid == 0) { lastrem_s = 0; npos_s = 0; }
  __syncthreads();

  {
    int cnt = __popc(act);
    for (int o = 1; o < 64; o <<= 1) cnt += __shfl_xor(cnt, o);
    if (lane == 0) atomicAdd(&npos_s, cnt);
  }
  unsigned sup = 0;

  // ---- phase B: triangular 8-round distributed resolve ----
  ROUND(0, X, Y) ROUND(1, Y, X) ROUND(2, X, Y) ROUND(3, Y, X)
  ROUND(4, X, Y) ROUND(5, Y, X) ROUND(6, X, Y) ROUND(7, Y, X)

  __syncthreads();

  // ---- phase C: prefix popcounts via wave scan, npick, ev2rank, fpr ----
  if (tid < 64) {
    int v = __popc(pm_lds[tid]);
    int inc = v;
    for (int o = 1; o < 64; o <<= 1) {
      int t = __shfl_up(inc, o);
      if (lane >= o) inc += t;
    }
    pre_s[tid] = (unsigned)(inc - v);        // exclusive prefix
    if (tid == 63) npick_s = inc;
  }
  __syncthreads();
  if (wave == 0) {
    unsigned wbits = pm_lds[lane];
    int e = (int)pre_s[lane];
    while (wbits) {
      int bpos = __ffs(wbits) - 1; wbits &= wbits - 1;
      int rank = lane * 32 + bpos;
      ev_s[e] = (unsigned short)rank;
      atomicMin(&fpr_s[(int)gts_s[rank]], rank);
      e++;
    }
  }
  __syncthreads();

  // ---- phase D: per-box event contributions via fsc (batched gathers) ----
  const int P = npick_s;
  {
    const int j0 = tid, j1 = tid + 512, j2 = tid + 1024, j3 = tid + 1536;
    const int c0 = fsc_s[j0], c1 = fsc_s[j1], c2 = fsc_s[j2], c3 = fsc_s[j3];
    uint2 v0 = make_uint2(0, 0), v1 = v0, v2 = v0, v3 = v0;
    if (c0 != 255) v0 = Cb[(size_t)c0 * 2048 + j0];
    if (c1 != 255) v1 = Cb[(size_t)c1 * 2048 + j1];
    if (c2 != 255) v2 = Cb[(size_t)c2 * 2048 + j2];
    if (c3 != 255) v3 = Cb[(size_t)c3 * 2048 + j3];

#define PROCD(J, C, V)                                                         \
  {                                                                            \
    int gj = (int)gts_s[J];                                                    \
    if ((C) != 255 && gj >= 0) {                                               \
      unsigned m0 = V.x & pm_lds[2 * (C)];                                     \
      unsigned m1 = V.y & pm_lds[2 * (C) + 1];                                 \
      int frank = m0 ? ((C) * 64 + __ffs(m0) - 1)                              \
                     : ((C) * 64 + 32 + __ffs(m1) - 1);                        \
      if (frank != (J)) {                                                      \
        int e = (int)pre_s[frank >> 5] +                                       \
                __popc(pm_lds[frank >> 5] & ((1u << (frank & 31)) - 1u));      \
        if (e == P - 1) lastrem_s = 1;                                         \
        int gt = (int)gts_s[frank];                                            \
        if (gj != gt) {                                                        \
          atomicOr(&hp_s[e >> 5], 1u << (e & 31));                             \
          if (fpr_s[gj] > frank) {                                             \
            atomicAdd(&qs_s[e], pers[b * BN + (J)]);                           \
            atomicAdd(&qc_s[e], 1);                                            \
          }                                                                    \
        }                                                                      \
      }                                                                        \
    }                                                                          \
  }

    PROCD(j0, c0, v0)
    PROCD(j1, c1, v1)
    PROCD(j2, c2, v2)
    PROCD(j3, c3, v3)
#undef PROCD
  }
  __syncthreads();

  // ---- phase E: event pass + block reduce + fused finalize ----
  const int lastrem = lastrem_s;
  const int npos = npos_s;
  float pull_l = 0.f, pcl = 0.f, push_l = 0.f, pshl = 0.f;
  for (int t = tid; t < P; t += 512) {
    int r = (int)ev_s[t];
    int g = (int)gts_s[r];
    int fp = fpr_s[g];
    bool seen = (fp < r);
    bool hr = (t < P - 1) || (lastrem != 0);
    if (seen) {
      pcl += 1.f;
      if (hr) {
        float4 bA = boxs[b * BN + fp];
        float4 bB = boxs[b * BN + r];
        float io = iou_box(bA, bB);
        pull_l += -logf(1.f - THR + fmaxf(io, EPSF)) * scs[b * BN + r];
      }
    }
    if (hr && ((hp_s[t >> 5] >> (t & 31)) & 1u)) {
      pshl += 1.f;
      push_l += qs_s[t] / ((float)qc_s[t] + EPSF);
    }
  }
  for (int o = 1; o < 64; o <<= 1) {
    pull_l += __shfl_xor(pull_l, o);
    pcl    += __shfl_xor(pcl, o);
    push_l += __shfl_xor(push_l, o);
    pshl   += __shfl_xor(pshl, o);
  }
  if (lane == 0) { redp[wave][0] = pull_l; redp[wave][1] = pcl; redp[wave][2] = push_l; redp[wave][3] = pshl; }
  __syncthreads();
  if (tid == 0) {
    float Ps = 0.f, Pc = 0.f, Ss = 0.f, Sc = 0.f;
    for (int w = 0; w < 8; ++w) { Ps += redp[w][0]; Pc += redp[w][1]; Ss += redp[w][2]; Sc += redp[w][3]; }
    float gate = (npos > 1) ? 1.f : 0.f;
    bp[b * 2 + 0] = gate * Ss / (Sc + EPSF);   // push
    bp[b * 2 + 1] = gate * Ps / (Pc + EPSF);   // pull
    __threadfence();
    int old = atomicAdd(arrive, 1);
    if (old == nb - 1) {                        // last block finalizes
      __threadfence();
      float ps = 0.f, pl = 0.f;
      for (int i = 0; i < nb; ++i) { ps += bp[2 * i]; pl += bp[2 * i + 1]; }
      float inv = 1.f / (float)nb;
      out[0] = ps * inv * PUSH_W;
      out[1] = pl * inv * PULL_W;
      *arrive = 0;                              // reset for next replay
    }
  }
}

// =============================== fallback path (round-1 kernel, proven) =====
constexpr int NT = 256;
constexpr int PT = BN / NT;
constexpr int NW = NT / 64;

__global__ void nms_finalize_kernel(const float* __restrict__ bp, float* __restrict__ out, int nb) {
  if (threadIdx.x == 0 && blockIdx.x == 0) {
    float ps = 0.f, pl = 0.f;
    for (int b = 0; b < nb; ++b) { ps += bp[2 * b]; pl += bp[2 * b + 1]; }
    float inv = 1.f / (float)nb;
    out[0] = ps * inv * PUSH_W;
    out[1] = pl * inv * PULL_W;
  }
}

__global__ __launch_bounds__(NT) void nms_loss_kernel(
    const int* __restrict__ gti_all, const float* __restrict__ gtb_all,
    const float* __restrict__ prop_all, float* __restrict__ out_bp)
{
  const int b = blockIdx.x;
  const int tid = threadIdx.x;
  const int lane = tid & 63;
  const int wave = tid >> 6;

  __shared__ float4 box[BN];
  __shared__ float sc[BN];
  __shared__ float per[BN];
  __shared__ int gts[BN];
  __shared__ unsigned char act[BN];
  __shared__ int rec[BG];
  __shared__ float rs[NW];
  __shared__ int ri[NW];
  __shared__ int rrem[NW];
  __shared__ int rqc[NW];
  __shared__ float rqs[NW];
  __shared__ int rany[NW];
  __shared__ int sh_nact;
  __shared__ int sh_ig;
  __shared__ float4 sh_ibox;

  const int* gti = gti_all + b * BN;
  const float* GB = gtb_all + b * BG * 4;
  const float* P = prop_all + (size_t)b * BN * 5;

  int local_pos = 0;
  for (int k = 0; k < PT; ++k) {
    int j = tid + k * NT;
    float x1 = P[j * 5 + 0], y1 = P[j * 5 + 1];
    float x2 = P[j * 5 + 2], y2 = P[j * 5 + 3];
    float s = P[j * 5 + 4];
    box[j] = make_float4(x1, y1, x2, y2);
    sc[j] = s;
    int g = gti[j];
    gts[j] = g;
    unsigned char a = (g >= 0) ? 1 : 0;
    act[j] = a;
    local_pos += a;
    float pv = 0.f;
    if (g >= 0) {
      float4 gb = make_float4(GB[g * 4], GB[g * 4 + 1], GB[g * 4 + 2], GB[g * 4 + 3]);
      float i2 = iou_box(gb, make_float4(x1, y1, x2, y2));
      pv = -logf(EPSF + i2) * s;
    }
    per[j] = pv;
  }
  if (tid < BG) rec[tid] = -1;
  for (int off = 32; off; off >>= 1) local_pos += __shfl_down(local_pos, off);
  if (lane == 0) rrem[wave] = local_pos;
  __syncthreads();
  int n_pos = 0;
  if (tid == 0) {
    for (int w = 0; w < NW; ++w) n_pos += rrem[w];
    sh_nact = n_pos;
  }
  float pull_sum = 0.f, push_sum = 0.f, pull_cnt = 0.f, push_cnt = 0.f;
  int t0_hasrem = 0;
  __syncthreads();

  while (true) {
    int nact = sh_nact;
    if (nact <= 0) break;
    float bs = -INFINITY;
    int bi = BN;
    for (int k = 0; k < PT; ++k) {
      int j = tid + k * NT;
      if (act[j]) {
        float s = sc[j];
        if (s > bs || (s == bs && j < bi)) { bs = s; bi = j; }
      }
    }
    for (int off = 32; off; off >>= 1) {
      float os = __shfl_down(bs, off);
      int oi = __shfl_down(bi, off);
      if (os > bs || (os == bs && oi < bi)) { bs = os; bi = oi; }
    }
    if (lane == 0) { rs[wave] = bs; ri[wave] = bi; }
    __syncthreads();
    if (tid == 0) {
      float cs = rs[0]; int ci = ri[0];
      for (int w = 1; w < NW; ++w)
        if (rs[w] > cs || (rs[w] == cs && ri[w] < ci)) { cs = rs[w]; ci = ri[w]; }
      int i = ci;
      int ig = gts[i];
      act[i] = 0;
      t0_hasrem = (nact - 1 > 0);
      int r = rec[ig];
      if (r >= 0) {
        pull_cnt += 1.f;
        if (t0_hasrem) {
          float i2 = iou_box(box[r], box[i]);
          float m = fmaxf(i2, EPSF);
          pull_sum += -logf(1.f - THR + m) * sc[i];
        }
      } else {
        rec[ig] = i;
      }
      sh_ig = ig; sh_ibox = box[i];
    }
    __syncthreads();
    float4 ib = sh_ibox;
    int igx = sh_ig;
    int removed = 0, qcc = 0, anyp = 0;
    float qss = 0.f;
    for (int k = 0; k < PT; ++k) {
      int j = tid + k * NT;
      if (act[j]) {
        float i2 = iou_box(ib, box[j]);
        if (i2 > THR) {
          act[j] = 0;
          removed++;
          int gj = gts[j];
          if (gj != igx) {
            anyp = 1;
            if (rec[gj] < 0) { qcc++; qss += per[j]; }
          }
        }
      }
    }
    for (int off = 32; off; off >>= 1) {
      removed += __shfl_down(removed, off);
      qcc += __shfl_down(qcc, off);
      qss += __shfl_down(qss, off);
      anyp |= __shfl_down(anyp, off);
    }
    if (lane == 0) { rrem[wave] = removed; rqc[wave] = qcc; rqs[wave] = qss; rany[wave] = anyp; }
    __syncthreads();
    if (tid == 0) {
      int rm = 0, qct = 0, ap = 0; float qst = 0.f;
      for (int w = 0; w < NW; ++w) { rm += rrem[w]; qct += rqc[w]; qst += rqs[w]; ap |= rany[w]; }
      sh_nact = nact - 1 - rm;
      if (t0_hasrem && ap) {
        push_sum += qst / ((float)qct + EPSF);
        push_cnt += 1.f;
      }
    }
    __syncthreads();
  }

  if (tid == 0) {
    float gate = (n_pos > 1) ? 1.f : 0.f;
    out_bp[b * 2 + 0] = gate * push_sum / (push_cnt + EPSF);
    out_bp[b * 2 + 1] = gate * pull_sum / (pull_cnt + EPSF);
  }
}

// ============================================================== launch =====
extern "C" void kernel_launch(void* const* d_in, const int* in_sizes, int n_in,
                              void* d_out, int out_size, void* d_ws, size_t ws_size,
                              hipStream_t stream) {
  const int* gti = (const int*)d_in[1];
  const float* gtb = (const float*)d_in[2];
  const float* props = (const float*)d_in[3];
  float* out = (float*)d_out;
  const int nb = in_sizes[1] / BN;   // 8

  // ws layout (bytes)
  const size_t off_adj  = 0;                                    // nb*32*2048*8
  const size_t off_box  = off_adj  + (size_t)nb * BN * 64 * 4;  // nb*BN*16
  const size_t off_per  = off_box  + (size_t)nb * BN * 16;      // nb*BN*4
  const size_t off_sc   = off_per  + (size_t)nb * BN * 4;       // nb*BN*4
  const size_t off_gts  = off_sc   + (size_t)nb * BN * 4;       // nb*BN*2
  const size_t off_bp   = off_gts  + (size_t)nb * BN * 2;       // nb*2*4
  const size_t off_arr  = off_bp   + (size_t)nb * 2 * 4;        // 4
  const size_t needed   = off_arr + 64;

  if (ws_size >= needed && nb == 8) {
    char* ws = (char*)d_ws;
    uint2* adjC = (uint2*)(ws + off_adj);
    float4* boxs = (float4*)(ws + off_box);
    float* pers = (float*)(ws + off_per);
    float* scs = (float*)(ws + off_sc);
    short* gtss = (short*)(ws + off_gts);
    float* bp = (float*)(ws + off_bp);
    int* arrive = (int*)(ws + off_arr);

    k1_sort<<<nb * 32, 512, 0, stream>>>(gti, gtb, props, boxs, pers, gtss, scs, arrive);
    k2_adj<<<nb * 36, 512, 0, stream>>>(boxs, adjC);
    k3_fused<<<nb, 512, 0, stream>>>(boxs, pers, gtss, scs, adjC, bp, arrive, out, nb);
  } else {
    float* bp = (float*)d_ws;
    nms_loss_kernel<<<nb, NT, 0, stream>>>(gti, gtb, props, bp);
    nms_finalize_kernel<<<1, 64, 0, stream>>>(bp, out, nb);
  }
}

// Round 20
// 50.818 us; speedup vs baseline: 1.0489x; 1.0489x over previous
//
#include <hip/hip_runtime.h>
#include <math.h>
#include <limits.h>

#define EPSF 1e-6f
#define THR 0.5f
#define PUSH_W 1.0f
#define PULL_W 1.0f

constexpr int BN = 2048;    // proposals per batch
constexpr int BG = 64;      // gt boxes per batch

__device__ __forceinline__ float iou_box(float4 a, float4 b) {
  float aa = (a.z - a.x) * (a.w - a.y);
  float ab = (b.z - b.x) * (b.w - b.y);
  float w = fmaxf(fminf(a.z, b.z) - fmaxf(a.x, b.x), 0.f);
  float h = fmaxf(fminf(a.w, b.w) - fmaxf(a.y, b.y), 0.f);
  float inter = w * h;
  return inter / (aa + ab - inter + EPSF);
}

// ------------------------------- K1: rank-by-count sort (8 threads per row)
__global__ __launch_bounds__(512) void k1_sort(
    const int* __restrict__ gti_all, const float* __restrict__ gtb_all,
    const float* __restrict__ prop_all,
    float4* __restrict__ boxs, float* __restrict__ pers,
    short* __restrict__ gtss, float* __restrict__ scs,
    int* __restrict__ arrive)
{
  const int b = blockIdx.x & 7;        // batch
  const int sub = blockIdx.x >> 3;     // 0..31 (64 rows each)
  const int tid = threadIdx.x;
  __shared__ unsigned long long key[BN];   // 16 KB

  if (blockIdx.x == 0 && tid == 0) *arrive = 0;   // defensive reset (pre-k3)

  const float* P = prop_all + (size_t)b * BN * 5;
  const int* gti = gti_all + b * BN;
  const float* GB = gtb_all + b * BG * 4;

  for (int k = 0; k < 4; ++k) {
    int j = tid + k * 512;
    key[j] = ((unsigned long long)__float_as_uint(P[j * 5 + 4]) << 32) |
             (unsigned)(BN - 1 - j);
  }
  __syncthreads();

  const int r = sub * 64 + (tid >> 3);
  const int g8 = tid & 7;
  const unsigned long long myk = key[r];
  int cnt = 0;
  const ulonglong2* K2 = (const ulonglong2*)key;
#pragma unroll 8
  for (int i = 0; i < 128; ++i) {
    ulonglong2 kk = K2[g8 + 8 * i];    // 8-group, conflict-free
    cnt += (kk.x > myk) ? 1 : 0;
    cnt += (kk.y > myk) ? 1 : 0;
  }
  cnt += __shfl_down(cnt, 4, 8);
  cnt += __shfl_down(cnt, 2, 8);
  cnt += __shfl_down(cnt, 1, 8);
  if (g8 == 0) {
    const int rank = cnt;
    int idx = (BN - 1) - (int)(myk & 0xffffffffu);
    float x1 = P[idx * 5 + 0], y1 = P[idx * 5 + 1];
    float x2 = P[idx * 5 + 2], y2 = P[idx * 5 + 3];
    float s = __uint_as_float((unsigned)(myk >> 32));
    int g = gti[idx];
    float4 bx = make_float4(x1, y1, x2, y2);
    boxs[b * BN + rank] = bx;
    scs[b * BN + rank] = s;
    gtss[b * BN + rank] = (short)g;
    float pv = 0.f;
    if (g >= 0) {
      float4 gb = make_float4(GB[g * 4], GB[g * 4 + 1], GB[g * 4 + 2], GB[g * 4 + 3]);
      pv = -logf(EPSF + iou_box(gb, bx)) * s;
    }
    pers[b * BN + rank] = pv;
  }
}

// ------------------------------------------------------------- K2: adjacency
__global__ __launch_bounds__(512) void k2_adj(
    const float4* __restrict__ boxs, uint2* __restrict__ adjC)
{
  const int b  = blockIdx.x & 7;
  const int rg = (blockIdx.x >> 3) & 7;
  const int cg = blockIdx.x >> 6;        // 0..3
  const int tid = threadIdx.x;           // 0..511
  const int lane = tid & 63;
  const int w = tid >> 6;                // wave 0..7
  __shared__ float4 bs[512];             // 8 KB column tile

  const float4* B = boxs + b * BN;
  bs[tid] = B[cg * 512 + tid];

  const float4 r0 = B[rg * 256 +   0 + lane];
  const float4 r1 = B[rg * 256 +  64 + lane];
  const float4 r2 = B[rg * 256 + 128 + lane];
  const float4 r3 = B[rg * 256 + 192 + lane];
  const float a0 = (r0.z - r0.x) * (r0.w - r0.y) + EPSF;
  const float a1 = (r1.z - r1.x) * (r1.w - r1.y) + EPSF;
  const float a2 = (r2.z - r2.x) * (r2.w - r2.y) + EPSF;
  const float a3 = (r3.z - r3.x) * (r3.w - r3.y) + EPSF;
  __syncthreads();

  const float4* C = &bs[w * 64];
  unsigned lo0 = 0, lo1 = 0, lo2 = 0, lo3 = 0;
  unsigned hi0 = 0, hi1 = 0, hi2 = 0, hi3 = 0;

#define PRED(RR, AA, BJ, AB)                                              \
  (3.0f * (fmaxf(fminf(RR.z, BJ.z) - fmaxf(RR.x, BJ.x), 0.f) *            \
           fmaxf(fminf(RR.w, BJ.w) - fmaxf(RR.y, BJ.y), 0.f)) > AA + AB)

#pragma unroll 8
  for (int jj = 0; jj < 32; ++jj) {
    float4 bj = C[jj];                   // wave-uniform -> LDS broadcast
    float ab = (bj.z - bj.x) * (bj.w - bj.y);
    lo0 |= PRED(r0, a0, bj, ab) ? (1u << jj) : 0u;
    lo1 |= PRED(r1, a1, bj, ab) ? (1u << jj) : 0u;
    lo2 |= PRED(r2, a2, bj, ab) ? (1u << jj) : 0u;
    lo3 |= PRED(r3, a3, bj, ab) ? (1u << jj) : 0u;
  }
#pragma unroll 8
  for (int jj = 0; jj < 32; ++jj) {
    float4 bj = C[32 + jj];
    float ab = (bj.z - bj.x) * (bj.w - bj.y);
    hi0 |= PRED(r0, a0, bj, ab) ? (1u << jj) : 0u;
    hi1 |= PRED(r1, a1, bj, ab) ? (1u << jj) : 0u;
    hi2 |= PRED(r2, a2, bj, ab) ? (1u << jj) : 0u;
    hi3 |= PRED(r3, a3, bj, ab) ? (1u << jj) : 0u;
  }
#undef PRED

  const int c = cg * 8 + w;
  uint2* CO = adjC + ((size_t)b * 32 + c) * 2048;
  CO[rg * 256 +   0 + lane] = make_uint2(lo0, hi0);
  CO[rg * 256 +  64 + lane] = make_uint2(lo1, hi1);
  CO[rg * 256 + 128 + lane] = make_uint2(lo2, hi2);
  CO[rg * 256 + 192 + lane] = make_uint2(lo3, hi3);
}

// ---------- K3 fused: triangular 8-round resolve + fsc events + loss
#define QR(B, K, Q) B##_##K##_##Q

#define DECL16(B) \
  uint2 QR(B,0,0), QR(B,0,1), QR(B,0,2), QR(B,0,3), \
        QR(B,1,0), QR(B,1,1), QR(B,1,2), QR(B,1,3), \
        QR(B,2,0), QR(B,2,1), QR(B,2,2), QR(B,2,3), \
        QR(B,3,0), QR(B,3,1), QR(B,3,2), QR(B,3,3);

#define LOADCH(B, K, C) \
  QR(B,K,0) = Cb[(size_t)(C) * 2048 + wbase]; \
  QR(B,K,1) = Cb[(size_t)(C) * 2048 + wbase + 64]; \
  QR(B,K,2) = Cb[(size_t)(C) * 2048 + wbase + 128]; \
  QR(B,K,3) = Cb[(size_t)(C) * 2048 + wbase + 192];

#define LOAD16(B, RR) \
  LOADCH(B, 0, (RR)*4+0) LOADCH(B, 1, (RR)*4+1) \
  LOADCH(B, 2, (RR)*4+2) LOADCH(B, 3, (RR)*4+3)

// scalar-domain greedy pick: one ballot, then s_ff1 + readlane per pick
#define PICK(B, K, C)                                                          \
  {                                                                            \
    unsigned mybit = ((act >> (K)) & ~(supG >> (K))) & 1u;                     \
    unsigned long long cand = __ballot(mybit != 0u);                           \
    unsigned long long pickw = 0ull;                                           \
    while (cand) {                                                             \
      int bpos = (int)__ffsll(cand) - 1;                                       \
      pickw |= 1ull << bpos;                                                   \
      unsigned rlo = __builtin_amdgcn_readlane(QR(B,K,K).x, bpos);             \
      unsigned rhi = __builtin_amdgcn_readlane(QR(B,K,K).y, bpos);             \
      cand &= ~((((unsigned long long)rhi) << 32) | (unsigned long long)rlo);  \
      cand &= ~(1ull << bpos);                                                 \
    }                                                                          \
    if (lane == 0) {                                                           \
      pm_lds[2 * (C)] = (unsigned)pickw;                                       \
      pm_lds[2 * (C) + 1] = (unsigned)(pickw >> 32);                           \
    }                                                                          \
    if (pickw != 0ull) {                                                       \
      unsigned pwlo = (unsigned)pickw, pwhi = (unsigned)(pickw >> 32);         \
      { unsigned hit = (QR(B,K,0).x & pwlo) | (QR(B,K,0).y & pwhi); supG |= (hit ? 1u : 0u); }      \
      { unsigned hit = (QR(B,K,1).x & pwlo) | (QR(B,K,1).y & pwhi); supG |= (hit ? 2u : 0u); }      \
      { unsigned hit = (QR(B,K,2).x & pwlo) | (QR(B,K,2).y & pwhi); supG |= (hit ? 4u : 0u); }      \
      { unsigned hit = (QR(B,K,3).x & pwlo) | (QR(B,K,3).y & pwhi); supG |= (hit ? 8u : 0u); }      \
    }                                                                          \
  }

#define APPLY(B, K, C)                                                         \
  {                                                                            \
    unsigned pwlo = pm_lds[2 * (C)], pwhi = pm_lds[2 * (C) + 1];               \
    if ((pwlo | pwhi) != 0u) {                                                 \
      unsigned nbits = 0;                                                      \
      { unsigned hit = (QR(B,K,0).x & pwlo) | (QR(B,K,0).y & pwhi); nbits |= hit ? 1u : 0u; }       \
      { unsigned hit = (QR(B,K,1).x & pwlo) | (QR(B,K,1).y & pwhi); nbits |= hit ? 2u : 0u; }       \
      { unsigned hit = (QR(B,K,2).x & pwlo) | (QR(B,K,2).y & pwhi); nbits |= hit ? 4u : 0u; }       \
      { unsigned hit = (QR(B,K,3).x & pwlo) | (QR(B,K,3).y & pwhi); nbits |= hit ? 8u : 0u; }       \
      unsigned flips = nbits & ~sup;                                           \
      sup |= nbits;                                                            \
      while (flips) {                                                          \
        int fq = __ffs(flips) - 1; flips &= flips - 1;                         \
        fsc_s[wbase + fq * 64] = (unsigned char)(C);                           \
      }                                                                        \
    }                                                                          \
  }

// triangular: wave o settled after round o -> loads gated wave>RR, APPLY wave>=RR
#define ROUND(RR, CUR, NXT)                                                    \
  {                                                                            \
    if (((RR) + 1 < 8) && (wave > (RR))) { LOAD16(NXT, (RR) + 1) }             \
    if (wave == (RR)) {                                                        \
      unsigned supG = sup;                                                     \
      PICK(CUR, 0, (RR)*4 + 0)                                                 \
      PICK(CUR, 1, (RR)*4 + 1)                                                 \
      PICK(CUR, 2, (RR)*4 + 2)                                                 \
      PICK(CUR, 3, (RR)*4 + 3)                                                 \
      asm volatile("s_waitcnt lgkmcnt(0)" ::: "memory");                       \
    }                                                                          \
    __builtin_amdgcn_s_barrier();                                              \
    asm volatile("" ::: "memory");                                             \
    if (wave >= (RR)) {                                                        \
      APPLY(CUR, 0, (RR)*4 + 0)                                                \
      APPLY(CUR, 1, (RR)*4 + 1)                                                \
      APPLY(CUR, 2, (RR)*4 + 2)                                                \
      APPLY(CUR, 3, (RR)*4 + 3)                                                \
    }                                                                          \
  }

__global__ __launch_bounds__(512, 1) void k3_fused(
    const float4* __restrict__ boxs, const float* __restrict__ pers,
    const short* __restrict__ gtss, const float* __restrict__ scs,
    const uint2* __restrict__ adjC, float* __restrict__ bp,
    int* __restrict__ arrive, float* __restrict__ out, int nb)
{
  const int b = blockIdx.x;
  const int tid = threadIdx.x;        // 0..511
  const int lane = tid & 63;
  const int wave = tid >> 6;          // 0..7

  __shared__ float qs_s[BN];          // 8 KB
  __shared__ int qc_s[BN];            // 8 KB
  __shared__ unsigned short ev_s[BN]; // 4 KB
  __shared__ short gts_s[BN];         // 4 KB
  __shared__ unsigned char fsc_s[BN]; // 2 KB
  __shared__ unsigned pm_lds[64];
  __shared__ unsigned pre_s[64];
  __shared__ int fpr_s[64];
  __shared__ unsigned hp_s[64];
  __shared__ int lastrem_s, npick_s, npos_s;
  __shared__ float redp[8][4];

  const uint2* Cb = adjC + (size_t)b * 32 * 2048;
  const int wbase = wave * 256 + lane;   // my q=0 rank

  // ---- phase A: init + stage gts ----
  for (int k = tid; k < BN / 2; k += 512)
    ((int*)gts_s)[k] = ((const int*)(gtss + b * BN))[k];
  for (int k = tid; k < BN; k += 512) { qs_s[k] = 0.f; qc_s[k] = 0; }
  for (int k = tid; k < BN; k += 512) fsc_s[k] = 255;
  if (tid < 64) { fpr_s[tid] = INT_MAX; hp_s[tid] = 0u; }
  if (tid == 0) { lastrem_s = 0; npos_s = 0; }
  __syncthreads();

  // ---- phase B: triangular 8-round distributed resolve ----
  DECL16(X)
  DECL16(Y)
  LOAD16(X, 0)

  unsigned act = 0;
  if (gts_s[wbase +   0] >= 0) act |= 1u;
  if (gts_s[wbase +  64] >= 0) act |= 2u;
  if (gts_s[wbase + 128] >= 0) act |= 4u;
  if (gts_s[wbase + 192] >= 0) act |= 8u;
  {
    int cnt = __popc(act);
    for (int o = 1; o < 64; o <<= 1) cnt += __shfl_xor(cnt, o);
    if (lane == 0) atomicAdd(&npos_s, cnt);
  }
  unsigned sup = 0;

  ROUND(0, X, Y) ROUND(1, Y, X) ROUND(2, X, Y) ROUND(3, Y, X)
  ROUND(4, X, Y) ROUND(5, Y, X) ROUND(6, X, Y) ROUND(7, Y, X)

  __syncthreads();

  // ---- phase C: prefix popcounts via wave scan, npick, ev2rank, fpr ----
  if (tid < 64) {
    int v = __popc(pm_lds[tid]);
    int inc = v;
    for (int o = 1; o < 64; o <<= 1) {
      int t = __shfl_up(inc, o);
      if (lane >= o) inc += t;
    }
    pre_s[tid] = (unsigned)(inc - v);        // exclusive prefix
    if (tid == 63) npick_s = inc;
  }
  __syncthreads();
  if (wave == 0) {
    unsigned wbits = pm_lds[lane];
    int e = (int)pre_s[lane];
    while (wbits) {
      int bpos = __ffs(wbits) - 1; wbits &= wbits - 1;
      int rank = lane * 32 + bpos;
      ev_s[e] = (unsigned short)rank;
      atomicMin(&fpr_s[(int)gts_s[rank]], rank);
      e++;
    }
  }
  __syncthreads();

  // ---- phase D: per-box event contributions via fsc (batched gathers) ----
  const int P = npick_s;
  {
    const int j0 = tid, j1 = tid + 512, j2 = tid + 1024, j3 = tid + 1536;
    const int c0 = fsc_s[j0], c1 = fsc_s[j1], c2 = fsc_s[j2], c3 = fsc_s[j3];
    uint2 v0 = make_uint2(0, 0), v1 = v0, v2 = v0, v3 = v0;
    if (c0 != 255) v0 = Cb[(size_t)c0 * 2048 + j0];
    if (c1 != 255) v1 = Cb[(size_t)c1 * 2048 + j1];
    if (c2 != 255) v2 = Cb[(size_t)c2 * 2048 + j2];
    if (c3 != 255) v3 = Cb[(size_t)c3 * 2048 + j3];

#define PROCD(J, C, V)                                                         \
  {                                                                            \
    int gj = (int)gts_s[J];                                                    \
    if ((C) != 255 && gj >= 0) {                                               \
      unsigned m0 = V.x & pm_lds[2 * (C)];                                     \
      unsigned m1 = V.y & pm_lds[2 * (C) + 1];                                 \
      int frank = m0 ? ((C) * 64 + __ffs(m0) - 1)                              \
                     : ((C) * 64 + 32 + __ffs(m1) - 1);                        \
      if (frank != (J)) {                                                      \
        int e = (int)pre_s[frank >> 5] +                                       \
                __popc(pm_lds[frank >> 5] & ((1u << (frank & 31)) - 1u));      \
        if (e == P - 1) lastrem_s = 1;                                         \
        int gt = (int)gts_s[frank];                                            \
        if (gj != gt) {                                                        \
          atomicOr(&hp_s[e >> 5], 1u << (e & 31));                             \
          if (fpr_s[gj] > frank) {                                             \
            atomicAdd(&qs_s[e], pers[b * BN + (J)]);                           \
            atomicAdd(&qc_s[e], 1);                                            \
          }                                                                    \
        }                                                                      \
      }                                                                        \
    }                                                                          \
  }

    PROCD(j0, c0, v0)
    PROCD(j1, c1, v1)
    PROCD(j2, c2, v2)
    PROCD(j3, c3, v3)
#undef PROCD
  }
  __syncthreads();

  // ---- phase E: event pass + block reduce + fused finalize ----
  const int lastrem = lastrem_s;
  const int npos = npos_s;
  float pull_l = 0.f, pcl = 0.f, push_l = 0.f, pshl = 0.f;
  for (int t = tid; t < P; t += 512) {
    int r = (int)ev_s[t];
    int g = (int)gts_s[r];
    int fp = fpr_s[g];
    bool seen = (fp < r);
    bool hr = (t < P - 1) || (lastrem != 0);
    if (seen) {
      pcl += 1.f;
      if (hr) {
        float4 bA = boxs[b * BN + fp];
        float4 bB = boxs[b * BN + r];
        float io = iou_box(bA, bB);
        pull_l += -logf(1.f - THR + fmaxf(io, EPSF)) * scs[b * BN + r];
      }
    }
    if (hr && ((hp_s[t >> 5] >> (t & 31)) & 1u)) {
      pshl += 1.f;
      push_l += qs_s[t] / ((float)qc_s[t] + EPSF);
    }
  }
  for (int o = 1; o < 64; o <<= 1) {
    pull_l += __shfl_xor(pull_l, o);
    pcl    += __shfl_xor(pcl, o);
    push_l += __shfl_xor(push_l, o);
    pshl   += __shfl_xor(pshl, o);
  }
  if (lane == 0) { redp[wave][0] = pull_l; redp[wave][1] = pcl; redp[wave][2] = push_l; redp[wave][3] = pshl; }
  __syncthreads();
  if (tid == 0) {
    float Ps = 0.f, Pc = 0.f, Ss = 0.f, Sc = 0.f;
    for (int w = 0; w < 8; ++w) { Ps += redp[w][0]; Pc += redp[w][1]; Ss += redp[w][2]; Sc += redp[w][3]; }
    float gate = (npos > 1) ? 1.f : 0.f;
    bp[b * 2 + 0] = gate * Ss / (Sc + EPSF);   // push
    bp[b * 2 + 1] = gate * Ps / (Pc + EPSF);   // pull
    __threadfence();
    int old = atomicAdd(arrive, 1);
    if (old == nb - 1) {                        // last block finalizes
      __threadfence();
      float ps = 0.f, pl = 0.f;
      for (int i = 0; i < nb; ++i) { ps += bp[2 * i]; pl += bp[2 * i + 1]; }
      float inv = 1.f / (float)nb;
      out[0] = ps * inv * PUSH_W;
      out[1] = pl * inv * PULL_W;
      *arrive = 0;                              // reset for next replay
    }
  }
}

// =============================== fallback path (round-1 kernel, proven) =====
constexpr int NT = 256;
constexpr int PT = BN / NT;
constexpr int NW = NT / 64;

__global__ void nms_finalize_kernel(const float* __restrict__ bp, float* __restrict__ out, int nb) {
  if (threadIdx.x == 0 && blockIdx.x == 0) {
    float ps = 0.f, pl = 0.f;
    for (int b = 0; b < nb; ++b) { ps += bp[2 * b]; pl += bp[2 * b + 1]; }
    float inv = 1.f / (float)nb;
    out[0] = ps * inv * PUSH_W;
    out[1] = pl * inv * PULL_W;
  }
}

__global__ __launch_bounds__(NT) void nms_loss_kernel(
    const int* __restrict__ gti_all, const float* __restrict__ gtb_all,
    const float* __restrict__ prop_all, float* __restrict__ out_bp)
{
  const int b = blockIdx.x;
  const int tid = threadIdx.x;
  const int lane = tid & 63;
  const int wave = tid >> 6;

  __shared__ float4 box[BN];
  __shared__ float sc[BN];
  __shared__ float per[BN];
  __shared__ int gts[BN];
  __shared__ unsigned char act[BN];
  __shared__ int rec[BG];
  __shared__ float rs[NW];
  __shared__ int ri[NW];
  __shared__ int rrem[NW];
  __shared__ int rqc[NW];
  __shared__ float rqs[NW];
  __shared__ int rany[NW];
  __shared__ int sh_nact;
  __shared__ int sh_ig;
  __shared__ float4 sh_ibox;

  const int* gti = gti_all + b * BN;
  const float* GB = gtb_all + b * BG * 4;
  const float* P = prop_all + (size_t)b * BN * 5;

  int local_pos = 0;
  for (int k = 0; k < PT; ++k) {
    int j = tid + k * NT;
    float x1 = P[j * 5 + 0], y1 = P[j * 5 + 1];
    float x2 = P[j * 5 + 2], y2 = P[j * 5 + 3];
    float s = P[j * 5 + 4];
    box[j] = make_float4(x1, y1, x2, y2);
    sc[j] = s;
    int g = gti[j];
    gts[j] = g;
    unsigned char a = (g >= 0) ? 1 : 0;
    act[j] = a;
    local_pos += a;
    float pv = 0.f;
    if (g >= 0) {
      float4 gb = make_float4(GB[g * 4], GB[g * 4 + 1], GB[g * 4 + 2], GB[g * 4 + 3]);
      float i2 = iou_box(gb, make_float4(x1, y1, x2, y2));
      pv = -logf(EPSF + i2) * s;
    }
    per[j] = pv;
  }
  if (tid < BG) rec[tid] = -1;
  for (int off = 32; off; off >>= 1) local_pos += __shfl_down(local_pos, off);
  if (lane == 0) rrem[wave] = local_pos;
  __syncthreads();
  int n_pos = 0;
  if (tid == 0) {
    for (int w = 0; w < NW; ++w) n_pos += rrem[w];
    sh_nact = n_pos;
  }
  float pull_sum = 0.f, push_sum = 0.f, pull_cnt = 0.f, push_cnt = 0.f;
  int t0_hasrem = 0;
  __syncthreads();

  while (true) {
    int nact = sh_nact;
    if (nact <= 0) break;
    float bs = -INFINITY;
    int bi = BN;
    for (int k = 0; k < PT; ++k) {
      int j = tid + k * NT;
      if (act[j]) {
        float s = sc[j];
        if (s > bs || (s == bs && j < bi)) { bs = s; bi = j; }
      }
    }
    for (int off = 32; off; off >>= 1) {
      float os = __shfl_down(bs, off);
      int oi = __shfl_down(bi, off);
      if (os > bs || (os == bs && oi < bi)) { bs = os; bi = oi; }
    }
    if (lane == 0) { rs[wave] = bs; ri[wave] = bi; }
    __syncthreads();
    if (tid == 0) {
      float cs = rs[0]; int ci = ri[0];
      for (int w = 1; w < NW; ++w)
        if (rs[w] > cs || (rs[w] == cs && ri[w] < ci)) { cs = rs[w]; ci = ri[w]; }
      int i = ci;
      int ig = gts[i];
      act[i] = 0;
      t0_hasrem = (nact - 1 > 0);
      int r = rec[ig];
      if (r >= 0) {
        pull_cnt += 1.f;
        if (t0_hasrem) {
          float i2 = iou_box(box[r], box[i]);
          float m = fmaxf(i2, EPSF);
          pull_sum += -logf(1.f - THR + m) * sc[i];
        }
      } else {
        rec[ig] = i;
      }
      sh_ig = ig; sh_ibox = box[i];
    }
    __syncthreads();
    float4 ib = sh_ibox;
    int igx = sh_ig;
    int removed = 0, qcc = 0, anyp = 0;
    float qss = 0.f;
    for (int k = 0; k < PT; ++k) {
      int j = tid + k * NT;
      if (act[j]) {
        float i2 = iou_box(ib, box[j]);
        if (i2 > THR) {
          act[j] = 0;
          removed++;
          int gj = gts[j];
          if (gj != igx) {
            anyp = 1;
            if (rec[gj] < 0) { qcc++; qss += per[j]; }
          }
        }
      }
    }
    for (int off = 32; off; off >>= 1) {
      removed += __shfl_down(removed, off);
      qcc += __shfl_down(qcc, off);
      qss += __shfl_down(qss, off);
      anyp |= __shfl_down(anyp, off);
    }
    if (lane == 0) { rrem[wave] = removed; rqc[wave] = qcc; rqs[wave] = qss; rany[wave] = anyp; }
    __syncthreads();
    if (tid == 0) {
      int rm = 0, qct = 0, ap = 0; float qst = 0.f;
      for (int w = 0; w < NW; ++w) { rm += rrem[w]; qct += rqc[w]; qst += rqs[w]; ap |= rany[w]; }
      sh_nact = nact - 1 - rm;
      if (t0_hasrem && ap) {
        push_sum += qst / ((float)qct + EPSF);
        push_cnt += 1.f;
      }
    }
    __syncthreads();
  }

  if (tid == 0) {
    float gate = (n_pos > 1) ? 1.f : 0.f;
    out_bp[b * 2 + 0] = gate * push_sum / (push_cnt + EPSF);
    out_bp[b * 2 + 1] = gate * pull_sum / (pull_cnt + EPSF);
  }
}

// ============================================================== launch =====
extern "C" void kernel_launch(void* const* d_in, const int* in_sizes, int n_in,
                              void* d_out, int out_size, void* d_ws, size_t ws_size,
                              hipStream_t stream) {
  const int* gti = (const int*)d_in[1];
  const float* gtb = (const float*)d_in[2];
  const float* props = (const float*)d_in[3];
  float* out = (float*)d_out;
  const int nb = in_sizes[1] / BN;   // 8

  // ws layout (bytes)
  const size_t off_adj  = 0;                                    // nb*32*2048*8
  const size_t off_box  = off_adj  + (size_t)nb * BN * 64 * 4;  // nb*BN*16
  const size_t off_per  = off_box  + (size_t)nb * BN * 16;      // nb*BN*4
  const size_t off_sc   = off_per  + (size_t)nb * BN * 4;       // nb*BN*4
  const size_t off_gts  = off_sc   + (size_t)nb * BN * 4;       // nb*BN*2
  const size_t off_bp   = off_gts  + (size_t)nb * BN * 2;       // nb*2*4
  const size_t off_arr  = off_bp   + (size_t)nb * 2 * 4;        // 4
  const size_t needed   = off_arr + 64;

  if (ws_size >= needed && nb == 8) {
    char* ws = (char*)d_ws;
    uint2* adjC = (uint2*)(ws + off_adj);
    float4* boxs = (float4*)(ws + off_box);
    float* pers = (float*)(ws + off_per);
    float* scs = (float*)(ws + off_sc);
    short* gtss = (short*)(ws + off_gts);
    float* bp = (float*)(ws + off_bp);
    int* arrive = (int*)(ws + off_arr);

    k1_sort<<<nb * 32, 512, 0, stream>>>(gti, gtb, props, boxs, pers, gtss, scs, arrive);
    k2_adj<<<nb * 32, 512, 0, stream>>>(boxs, adjC);
    k3_fused<<<nb, 512, 0, stream>>>(boxs, pers, gtss, scs, adjC, bp, arrive, out, nb);
  } else {
    float* bp = (float*)d_ws;
    nms_loss_kernel<<<nb, NT, 0, stream>>>(gti, gtb, props, bp);
    nms_finalize_kernel<<<1, 64, 0, stream>>>(bp, out, nb);
  }
}